// Round 4
// baseline (357.724 us; speedup 1.0000x reference)
//
#include <hip/hip_runtime.h>
#include <hip/hip_bf16.h>
#include <math.h>

#define N_NODES 100000
#define M_EDGES 800000
#define HID 128
#define HEADS 8
#define DH 16
#define SCAN_NB ((N_NODES + 1023) / 1024)   // 98 blocks of 1024 counts

typedef __attribute__((ext_vector_type(8))) short short8;   // 8 x bf16 (4 VGPRs)
typedef __attribute__((ext_vector_type(4))) float floatx4;  // MFMA accumulator

__device__ __forceinline__ ushort f32_to_bf16(float x) {
    __hip_bfloat16 h = __float2bfloat16(x);   // RNE
    union { __hip_bfloat16 h; ushort u; } c; c.h = h;
    return c.u;
}
__device__ __forceinline__ float bf16_bits_to_f32(ushort u) {
    union { unsigned int i; float f; } c; c.i = ((unsigned int)u) << 16;
    return c.f;
}
__device__ __forceinline__ float bf16pair_lo(unsigned int p) {
    union { unsigned int i; float f; } c; c.i = p << 16; return c.f;
}
__device__ __forceinline__ float bf16pair_hi(unsigned int p) {
    union { unsigned int i; float f; } c; c.i = p & 0xffff0000u; return c.f;
}

// ---------------------------------------------------------------------------
// Stage a 128x128 FP32 weight matrix into LDS as bf16 in MFMA B-fragment
// order (convert-on-stage; weights are L2-resident broadcast, ~64 KB).
// Fragment layout: lds[(ks*8+t)*512 + lane*8 + j] = W[t*16+(lane&15)][ks*32+(lane>>4)*8+j]
// ---------------------------------------------------------------------------
__device__ __forceinline__ void stage_w_cvt(const float* __restrict__ W,
                                            ushort* __restrict__ lds, int tid)
{
    #pragma unroll
    for (int i = 0; i < 8; ++i) {
        int idx  = i * 256 + tid;       // 0..2047 chunks of 8 ushorts
        int f    = idx >> 6;
        int lane = idx & 63;
        int t    = f & 7, ks = f >> 3;
        int row  = t * 16 + (lane & 15);
        int col  = ks * 32 + (lane >> 4) * 8;
        const float* src = W + row * HID + col;
        float4 f0 = *(const float4*)(src);
        float4 f1 = *(const float4*)(src + 4);
        ushort4 o0, o1;
        o0.x = f32_to_bf16(f0.x); o0.y = f32_to_bf16(f0.y);
        o0.z = f32_to_bf16(f0.z); o0.w = f32_to_bf16(f0.w);
        o1.x = f32_to_bf16(f1.x); o1.y = f32_to_bf16(f1.y);
        o1.z = f32_to_bf16(f1.z); o1.w = f32_to_bf16(f1.w);
        *(ushort4*)(lds + idx * 8)     = o0;
        *(ushort4*)(lds + idx * 8 + 4) = o1;
    }
}

// ---------------------------------------------------------------------------
// Q/K/V projection via bf16 MFMA, LDS-staged (convert-on-stage) weights,
// 128 rows/block.  q and v go into the INTERLEAVED qv buffer (node stride
// 256: q then v); k goes into its own [node][128] array.
// ---------------------------------------------------------------------------
__global__ __launch_bounds__(256) void qkv_mfma_kernel(
    const float* __restrict__ feats,
    const float* __restrict__ Wq, const float* __restrict__ Wk, const float* __restrict__ Wv,
    ushort* __restrict__ qv16, ushort* __restrict__ k16)
{
    __shared__ ushort wlds[16384];                 // 32 KB, one W at a time
    const int tid  = threadIdx.x;
    const int wave = tid >> 6;
    const int lane = tid & 63;
    const int row0 = blockIdx.x * 128 + wave * 32;
    const int lrow = lane & 15;
    const int lk   = (lane >> 4) * 8;
    const int crow = (lane >> 4) * 4;

    // A fragments for 2 tiles x 4 ks, converted fp32->bf16 in-reg (N%16==0).
    short8 afrag[2][4];
    bool tvalid[2];
    #pragma unroll
    for (int r = 0; r < 2; ++r) {
        int rr = row0 + r * 16;
        tvalid[r] = (rr < N_NODES);
        const float* arow = feats + (size_t)((tvalid[r] ? rr : 0) + lrow) * HID + lk;
        #pragma unroll
        for (int ks = 0; ks < 4; ++ks) {
            float4 f0 = *(const float4*)(arow + ks * 32);
            float4 f1 = *(const float4*)(arow + ks * 32 + 4);
            short8 a;
            a[0] = (short)f32_to_bf16(f0.x); a[1] = (short)f32_to_bf16(f0.y);
            a[2] = (short)f32_to_bf16(f0.z); a[3] = (short)f32_to_bf16(f0.w);
            a[4] = (short)f32_to_bf16(f1.x); a[5] = (short)f32_to_bf16(f1.y);
            a[6] = (short)f32_to_bf16(f1.z); a[7] = (short)f32_to_bf16(f1.w);
            afrag[r][ks] = a;
        }
    }

    const float* Ws[3] = {Wq, Wk, Wv};
    // output bases and per-node strides: q -> qv+0 (256), k -> k16 (128), v -> qv+128 (256)
    ushort* Ob[3]; int Ostride[3];
    Ob[0] = qv16;       Ostride[0] = 256;
    Ob[1] = k16;        Ostride[1] = 128;
    Ob[2] = qv16 + 128; Ostride[2] = 256;

    #pragma unroll
    for (int w = 0; w < 3; ++w) {
        __syncthreads();                           // prior reads of wlds done
        stage_w_cvt(Ws[w], wlds, tid);
        __syncthreads();

        floatx4 acc[2][8];
        #pragma unroll
        for (int r = 0; r < 2; ++r)
            #pragma unroll
            for (int t = 0; t < 8; ++t) acc[r][t] = (floatx4)(0.f);

        #pragma unroll
        for (int ks = 0; ks < 4; ++ks) {
            short8 B[8];
            #pragma unroll
            for (int t = 0; t < 8; ++t)
                B[t] = *(const short8*)&wlds[(ks * 8 + t) * 512 + lane * 8];
            #pragma unroll
            for (int t = 0; t < 8; ++t) {
                acc[0][t] = __builtin_amdgcn_mfma_f32_16x16x32_bf16(B[t], afrag[0][ks], acc[0][t], 0, 0, 0);
                acc[1][t] = __builtin_amdgcn_mfma_f32_16x16x32_bf16(B[t], afrag[1][ks], acc[1][t], 0, 0, 0);
            }
        }

        #pragma unroll
        for (int r = 0; r < 2; ++r) {
            if (tvalid[r]) {
                ushort* O = Ob[w] + (size_t)(row0 + r * 16 + lrow) * Ostride[w];
                #pragma unroll
                for (int t = 0; t < 8; ++t) {
                    ushort4 o;
                    o.x = f32_to_bf16(acc[r][t][0]); o.y = f32_to_bf16(acc[r][t][1]);
                    o.z = f32_to_bf16(acc[r][t][2]); o.w = f32_to_bf16(acc[r][t][3]);
                    *(ushort4*)(O + t * 16 + crow) = o;
                }
            }
        }
    }
}

// ---------------------------------------------------------------------------
// CSR build: standalone histogram (slim blocks, full occupancy) -> 3-stage
// device-wide scan -> fill (stores kj direct).
// ---------------------------------------------------------------------------
__global__ __launch_bounds__(256) void hist_kernel(
    const int* __restrict__ idx_ji, int* __restrict__ count)
{
    int m = blockIdx.x * 256 + threadIdx.x;
    if (m < M_EDGES) atomicAdd(&count[idx_ji[m]], 1);
}

__global__ __launch_bounds__(256) void scan_blocksum_kernel(
    const int* __restrict__ count, int* __restrict__ blocksum)
{
    __shared__ int s[256];
    const int tid = threadIdx.x;
    const int base = blockIdx.x * 1024 + tid * 4;
    int sum = 0;
    if (base + 3 < N_NODES) {
        int4 c = *(const int4*)(count + base);
        sum = c.x + c.y + c.z + c.w;
    } else {
        #pragma unroll
        for (int j = 0; j < 4; ++j) if (base + j < N_NODES) sum += count[base + j];
    }
    s[tid] = sum;
    __syncthreads();
    for (int off = 128; off > 0; off >>= 1) {
        if (tid < off) s[tid] += s[tid + off];
        __syncthreads();
    }
    if (tid == 0) blocksum[blockIdx.x] = s[0];
}

__global__ __launch_bounds__(128) void scan_top_kernel(int* __restrict__ blocksum)
{
    __shared__ int s[128];
    const int t = threadIdx.x;
    int v = (t < SCAN_NB) ? blocksum[t] : 0;
    s[t] = v;
    __syncthreads();
    for (int off = 1; off < 128; off <<= 1) {
        int x = (t >= off) ? s[t - off] : 0;
        __syncthreads();
        s[t] += x;
        __syncthreads();
    }
    if (t < SCAN_NB) blocksum[t] = s[t] - v;   // exclusive
}

__global__ __launch_bounds__(256) void scan_write_kernel(
    const int* __restrict__ count, const int* __restrict__ blocksum,
    int* __restrict__ offsets, int* __restrict__ cursor)
{
    __shared__ int s[256];
    const int tid = threadIdx.x;
    const int base = blockIdx.x * 1024 + tid * 4;
    int c0 = 0, c1 = 0, c2 = 0, c3 = 0;
    if (base + 3 < N_NODES) {
        int4 c = *(const int4*)(count + base);
        c0 = c.x; c1 = c.y; c2 = c.z; c3 = c.w;
    } else {
        if (base     < N_NODES) c0 = count[base];
        if (base + 1 < N_NODES) c1 = count[base + 1];
        if (base + 2 < N_NODES) c2 = count[base + 2];
        if (base + 3 < N_NODES) c3 = count[base + 3];
    }
    const int tsum = c0 + c1 + c2 + c3;
    s[tid] = tsum;
    __syncthreads();
    for (int off = 1; off < 256; off <<= 1) {
        int x = (tid >= off) ? s[tid - off] : 0;
        __syncthreads();
        s[tid] += x;
        __syncthreads();
    }
    int o0 = s[tid] - tsum + blocksum[blockIdx.x];
    int o1 = o0 + c0, o2 = o1 + c1, o3 = o2 + c2;
    if (base + 3 < N_NODES) {
        *(int4*)(offsets + base) = make_int4(o0, o1, o2, o3);
        *(int4*)(cursor  + base) = make_int4(o0, o1, o2, o3);
    } else {
        if (base     < N_NODES) { offsets[base]     = o0; cursor[base]     = o0; }
        if (base + 1 < N_NODES) { offsets[base + 1] = o1; cursor[base + 1] = o1; }
        if (base + 2 < N_NODES) { offsets[base + 2] = o2; cursor[base + 2] = o2; }
        if (base + 3 < N_NODES) { offsets[base + 3] = o3; cursor[base + 3] = o3; }
    }
}

__global__ __launch_bounds__(256) void fill_kernel(
    const int* __restrict__ idx_ji, const int* __restrict__ idx_kj,
    int* __restrict__ cursor, int* __restrict__ edge_kj)
{
    int m = blockIdx.x * 256 + threadIdx.x;
    if (m < M_EDGES) {
        int pos = atomicAdd(&cursor[idx_ji[m]], 1);
        edge_kj[pos] = idx_kj[m];
    }
}

// ---------------------------------------------------------------------------
// Fused attention + normalized aggregation: 16 LANES PER NODE (4 nodes/wave),
// 8 channels/lane via uint4 (16B) gathers from the interleaved qv buffer.
// Measured floor: ~64 us, 202 MB fetch @ ~3.6 TB/s beyond-L2 (R0/R2).
// ---------------------------------------------------------------------------
__device__ __forceinline__ float dot8(const uint4& qp, const float* kn) {
    const unsigned int* q = (const unsigned int*)&qp;
    float p = 0.f;
    #pragma unroll
    for (int j = 0; j < 4; ++j)
        p += bf16pair_lo(q[j]) * kn[2*j] + bf16pair_hi(q[j]) * kn[2*j+1];
    return p;
}
__device__ __forceinline__ void axpy8(float* acc, float s, const uint4& vp) {
    const unsigned int* v = (const unsigned int*)&vp;
    #pragma unroll
    for (int j = 0; j < 4; ++j) {
        acc[2*j]   += s * bf16pair_lo(v[j]);
        acc[2*j+1] += s * bf16pair_hi(v[j]);
    }
}

__global__ __launch_bounds__(256) void aggregate_kernel(
    const int* __restrict__ edge_kj, const int* __restrict__ offsets,
    const int* __restrict__ count, const ushort* __restrict__ qv16,
    const ushort* __restrict__ k16, ushort* __restrict__ agg16)
{
    const int gid  = blockIdx.x * 256 + threadIdx.x;
    const int node = gid >> 4;
    const int l16  = threadIdx.x & 15;
    if (node >= N_NODES) return;

    const int deg  = count[node];
    const int base = offsets[node];

    // k fragment: 8 channels of this node's k row
    float kn[8];
    {
        uint4 kp = *(const uint4*)(k16 + (size_t)node * HID + l16 * 8);
        const unsigned int* kw = (const unsigned int*)&kp;
        #pragma unroll
        for (int j = 0; j < 4; ++j) {
            kn[2*j]   = bf16pair_lo(kw[j]);
            kn[2*j+1] = bf16pair_hi(kw[j]);
        }
    }

    float acc[8] = {0.f,0.f,0.f,0.f,0.f,0.f,0.f,0.f};
    float d = 0.f;

    const ushort* qvb = qv16 + l16 * 8;

    int e = 0;
    for (; e + 4 <= deg; e += 4) {
        const int kj0 = edge_kj[base + e + 0];
        const int kj1 = edge_kj[base + e + 1];
        const int kj2 = edge_kj[base + e + 2];
        const int kj3 = edge_kj[base + e + 3];
        const ushort* r0 = qvb + (size_t)kj0 * 256;
        const ushort* r1 = qvb + (size_t)kj1 * 256;
        const ushort* r2 = qvb + (size_t)kj2 * 256;
        const ushort* r3 = qvb + (size_t)kj3 * 256;
        uint4 qp0 = *(const uint4*)r0;  uint4 vp0 = *(const uint4*)(r0 + 128);
        uint4 qp1 = *(const uint4*)r1;  uint4 vp1 = *(const uint4*)(r1 + 128);
        uint4 qp2 = *(const uint4*)r2;  uint4 vp2 = *(const uint4*)(r2 + 128);
        uint4 qp3 = *(const uint4*)r3;  uint4 vp3 = *(const uint4*)(r3 + 128);

        float p0 = dot8(qp0, kn);
        float p1 = dot8(qp1, kn);
        float p2 = dot8(qp2, kn);
        float p3 = dot8(qp3, kn);
        p0 += __shfl_xor(p0, 1);
        p1 += __shfl_xor(p1, 1);
        p2 += __shfl_xor(p2, 1);
        p3 += __shfl_xor(p3, 1);
        float s0 = __expf(fmaxf(p0, 0.2f * p0));
        float s1 = __expf(fmaxf(p1, 0.2f * p1));
        float s2 = __expf(fmaxf(p2, 0.2f * p2));
        float s3 = __expf(fmaxf(p3, 0.2f * p3));
        d += (s0 + s1) + (s2 + s3);
        axpy8(acc, s0, vp0);
        axpy8(acc, s1, vp1);
        axpy8(acc, s2, vp2);
        axpy8(acc, s3, vp3);
    }
    if (e + 2 <= deg) {
        const int kj0 = edge_kj[base + e];
        const int kj1 = edge_kj[base + e + 1];
        const ushort* r0 = qvb + (size_t)kj0 * 256;
        const ushort* r1 = qvb + (size_t)kj1 * 256;
        uint4 qp0 = *(const uint4*)r0;  uint4 vp0 = *(const uint4*)(r0 + 128);
        uint4 qp1 = *(const uint4*)r1;  uint4 vp1 = *(const uint4*)(r1 + 128);
        float p0 = dot8(qp0, kn);
        float p1 = dot8(qp1, kn);
        p0 += __shfl_xor(p0, 1);
        p1 += __shfl_xor(p1, 1);
        float s0 = __expf(fmaxf(p0, 0.2f * p0));
        float s1 = __expf(fmaxf(p1, 0.2f * p1));
        d += s0 + s1;
        axpy8(acc, s0, vp0);
        axpy8(acc, s1, vp1);
        e += 2;
    }
    if (e < deg) {
        const int kj0 = edge_kj[base + e];
        const ushort* r0 = qvb + (size_t)kj0 * 256;
        uint4 qp0 = *(const uint4*)r0;  uint4 vp0 = *(const uint4*)(r0 + 128);
        float p0 = dot8(qp0, kn);
        p0 += __shfl_xor(p0, 1);
        float s0 = __expf(fmaxf(p0, 0.2f * p0));
        d += s0;
        axpy8(acc, s0, vp0);
    }

    const float inv = (deg > 0) ? 1.f / d : 0.f;     // deg==0 -> zeros, not NaN
    uint4 o;
    unsigned int* ow = (unsigned int*)&o;
    #pragma unroll
    for (int j = 0; j < 4; ++j)
        ow[j] = (unsigned int)f32_to_bf16(acc[2*j] * inv)
              | ((unsigned int)f32_to_bf16(acc[2*j+1] * inv) << 16);
    *(uint4*)(agg16 + (size_t)node * HID + l16 * 8) = o;
}

// ---------------------------------------------------------------------------
// MLP split into two qkv-shaped kernels (32 KB LDS each, 2 barriers each,
// 5 blocks/CU LDS-cap vs 2 for the fused 64 KB version).  h1 round-trips
// through global as bf16 [N][128]; the C-layout->A-layout transpose happens
// for free through the memory layout (ushort4 C-writes, short8 A-reads).
// ---------------------------------------------------------------------------
__global__ __launch_bounds__(256) void mlp1_kernel(
    const ushort* __restrict__ agg16,
    const float* __restrict__ W1, const float* __restrict__ b1,
    ushort* __restrict__ h1_16)
{
    __shared__ ushort wlds[16384];    // 32 KB
    const int tid  = threadIdx.x;
    const int wave = tid >> 6;
    const int lane = tid & 63;
    const int row0 = blockIdx.x * 128 + wave * 32;
    const int lrow = lane & 15;
    const int lk   = (lane >> 4) * 8;
    const int crow = (lane >> 4) * 4;

    short8 afrag[2][4];
    bool tvalid[2];
    #pragma unroll
    for (int r = 0; r < 2; ++r) {
        int rr = row0 + r * 16;
        tvalid[r] = (rr < N_NODES);
        const ushort* arow = agg16 + (size_t)((tvalid[r] ? rr : 0) + lrow) * HID + lk;
        #pragma unroll
        for (int ks = 0; ks < 4; ++ks)
            afrag[r][ks] = *(const short8*)(arow + ks * 32);
    }

    stage_w_cvt(W1, wlds, tid);
    __syncthreads();

    floatx4 acc[2][8];
    #pragma unroll
    for (int r = 0; r < 2; ++r)
        #pragma unroll
        for (int t = 0; t < 8; ++t) acc[r][t] = (floatx4)(0.f);
    #pragma unroll
    for (int ks = 0; ks < 4; ++ks) {
        short8 B[8];
        #pragma unroll
        for (int t = 0; t < 8; ++t)
            B[t] = *(const short8*)&wlds[(ks * 8 + t) * 512 + lane * 8];
        #pragma unroll
        for (int t = 0; t < 8; ++t) {
            acc[0][t] = __builtin_amdgcn_mfma_f32_16x16x32_bf16(B[t], afrag[0][ks], acc[0][t], 0, 0, 0);
            acc[1][t] = __builtin_amdgcn_mfma_f32_16x16x32_bf16(B[t], afrag[1][ks], acc[1][t], 0, 0, 0);
        }
    }

    #pragma unroll
    for (int r = 0; r < 2; ++r) {
        if (tvalid[r]) {
            ushort* O = h1_16 + (size_t)(row0 + r * 16 + lrow) * HID;
            #pragma unroll
            for (int t = 0; t < 8; ++t) {
                float4 bias = *(const float4*)(b1 + t * 16 + crow);
                ushort4 o;
                o.x = f32_to_bf16(fmaxf(acc[r][t][0] + bias.x, 0.f));
                o.y = f32_to_bf16(fmaxf(acc[r][t][1] + bias.y, 0.f));
                o.z = f32_to_bf16(fmaxf(acc[r][t][2] + bias.z, 0.f));
                o.w = f32_to_bf16(fmaxf(acc[r][t][3] + bias.w, 0.f));
                *(ushort4*)(O + t * 16 + crow) = o;
            }
        }
    }
}

__global__ __launch_bounds__(256) void mlp2_kernel(
    const ushort* __restrict__ h1_16, const ushort* __restrict__ qv16,
    const float* __restrict__ W2, const float* __restrict__ b2,
    float* __restrict__ out)
{
    __shared__ ushort wlds[16384];    // 32 KB
    const int tid  = threadIdx.x;
    const int wave = tid >> 6;
    const int lane = tid & 63;
    const int row0 = blockIdx.x * 128 + wave * 32;
    const int lrow = lane & 15;
    const int lk   = (lane >> 4) * 8;
    const int crow = (lane >> 4) * 4;

    short8 hfrag[2][4];
    bool tvalid[2];
    #pragma unroll
    for (int r = 0; r < 2; ++r) {
        int rr = row0 + r * 16;
        tvalid[r] = (rr < N_NODES);
        const ushort* hrow = h1_16 + (size_t)((tvalid[r] ? rr : 0) + lrow) * HID + lk;
        #pragma unroll
        for (int ks = 0; ks < 4; ++ks)
            hfrag[r][ks] = *(const short8*)(hrow + ks * 32);
    }

    stage_w_cvt(W2, wlds, tid);
    __syncthreads();

    floatx4 acc[2][8];
    #pragma unroll
    for (int r = 0; r < 2; ++r)
        #pragma unroll
        for (int t = 0; t < 8; ++t) acc[r][t] = (floatx4)(0.f);
    #pragma unroll
    for (int ks = 0; ks < 4; ++ks) {
        short8 B[8];
        #pragma unroll
        for (int t = 0; t < 8; ++t)
            B[t] = *(const short8*)&wlds[(ks * 8 + t) * 512 + lane * 8];
        #pragma unroll
        for (int t = 0; t < 8; ++t) {
            acc[0][t] = __builtin_amdgcn_mfma_f32_16x16x32_bf16(B[t], hfrag[0][ks], acc[0][t], 0, 0, 0);
            acc[1][t] = __builtin_amdgcn_mfma_f32_16x16x32_bf16(B[t], hfrag[1][ks], acc[1][t], 0, 0, 0);
        }
    }

    #pragma unroll
    for (int r = 0; r < 2; ++r) {
        if (tvalid[r]) {
            const size_t nrow = (size_t)(row0 + r * 16 + lrow);
            const ushort* vrow = qv16 + nrow * 256 + 128;
            float* orow = out + nrow * HID;
            #pragma unroll
            for (int t = 0; t < 8; ++t) {
                float4 bias = *(const float4*)(b2 + t * 16 + crow);
                ushort4 vv = *(const ushort4*)(vrow + t * 16 + crow);
                float4 o;
                o.x = bf16_bits_to_f32(vv.x) + fmaxf(acc[r][t][0] + bias.x, 0.f);
                o.y = bf16_bits_to_f32(vv.y) + fmaxf(acc[r][t][1] + bias.y, 0.f);
                o.z = bf16_bits_to_f32(vv.z) + fmaxf(acc[r][t][2] + bias.z, 0.f);
                o.w = bf16_bits_to_f32(vv.w) + fmaxf(acc[r][t][3] + bias.w, 0.f);
                *(float4*)(orow + t * 16 + crow) = o;
            }
        }
    }
}

extern "C" void kernel_launch(void* const* d_in, const int* in_sizes, int n_in,
                              void* d_out, int out_size, void* d_ws, size_t ws_size,
                              hipStream_t stream) {
    const float* feats  = (const float*)d_in[0];
    const int*   idx_kj = (const int*)d_in[1];
    const int*   idx_ji = (const int*)d_in[2];
    const float* Wv     = (const float*)d_in[3];
    const float* Wq     = (const float*)d_in[4];
    const float* Wk     = (const float*)d_in[5];
    const float* W1     = (const float*)d_in[6];
    const float* b1     = (const float*)d_in[7];
    const float* W2     = (const float*)d_in[8];
    const float* b2     = (const float*)d_in[9];
    float* out = (float*)d_out;

    // workspace layout
    ushort* qv16    = (ushort*)d_ws;                        // [N][256]: q | v
    ushort* k16     = qv16    + (size_t)N_NODES * 256;      // [N][128]
    ushort* agg16   = k16     + (size_t)N_NODES * HID;      // [N][128]
    ushort* h1_16   = agg16   + (size_t)N_NODES * HID;      // [N][128]
    int* count      = (int*)(h1_16 + (size_t)N_NODES * HID);
    int* offsets    = count + N_NODES;
    int* cursor     = offsets + N_NODES;
    int* blocksum   = cursor + N_NODES;
    int* edge_kj    = blocksum + ((SCAN_NB + 3) & ~3);

    hipMemsetAsync(count, 0, N_NODES * sizeof(int), stream);

    qkv_mfma_kernel<<<(N_NODES + 127) / 128, 256, 0, stream>>>(
        feats, Wq, Wk, Wv, qv16, k16);

    hist_kernel<<<(M_EDGES + 255) / 256, 256, 0, stream>>>(idx_ji, count);
    scan_blocksum_kernel<<<SCAN_NB, 256, 0, stream>>>(count, blocksum);
    scan_top_kernel<<<1, 128, 0, stream>>>(blocksum);
    scan_write_kernel<<<SCAN_NB, 256, 0, stream>>>(count, blocksum, offsets, cursor);
    fill_kernel<<<(M_EDGES + 255) / 256, 256, 0, stream>>>(idx_ji, idx_kj, cursor, edge_kj);

    aggregate_kernel<<<((size_t)N_NODES * 16 + 255) / 256, 256, 0, stream>>>(
        edge_kj, offsets, count, qv16, k16, agg16);

    mlp1_kernel<<<(N_NODES + 127) / 128, 256, 0, stream>>>(
        agg16, W1, b1, h1_16);
    mlp2_kernel<<<(N_NODES + 127) / 128, 256, 0, stream>>>(
        h1_16, qv16, W2, b2, out);
}

// Round 5
// 322.843 us; speedup vs baseline: 1.1080x; 1.1080x over previous
//
#include <hip/hip_runtime.h>
#include <hip/hip_bf16.h>
#include <math.h>

#define N_NODES 100000
#define M_EDGES 800000
#define HID 128
#define HEADS 8
#define DH 16
#define SCAN_NB ((N_NODES + 1023) / 1024)   // 98 blocks of 1024 counts

typedef __attribute__((ext_vector_type(8))) short short8;   // 8 x bf16 (4 VGPRs)
typedef __attribute__((ext_vector_type(4))) float floatx4;  // MFMA accumulator

__device__ __forceinline__ ushort f32_to_bf16(float x) {
    __hip_bfloat16 h = __float2bfloat16(x);   // RNE
    union { __hip_bfloat16 h; ushort u; } c; c.h = h;
    return c.u;
}
__device__ __forceinline__ float bf16_bits_to_f32(ushort u) {
    union { unsigned int i; float f; } c; c.i = ((unsigned int)u) << 16;
    return c.f;
}
__device__ __forceinline__ float bf16pair_lo(unsigned int p) {
    union { unsigned int i; float f; } c; c.i = p << 16; return c.f;
}
__device__ __forceinline__ float bf16pair_hi(unsigned int p) {
    union { unsigned int i; float f; } c; c.i = p & 0xffff0000u; return c.f;
}

// ---------------------------------------------------------------------------
// Convert the five 128x128 weight matrices -> bf16 DIRECTLY IN MFMA B-FRAGMENT
// ORDER (out[(ks*8+t)*512 + lane*8 + j] = W[t*16+(lane&15)][ks*32+(lane>>4)*8+j]).
// Consumers stage with a pure linear copy.  Also zeroes count[] (fused memset).
// ---------------------------------------------------------------------------
__global__ __launch_bounds__(256) void cvt_w_kernel(
    const float* __restrict__ Wq, const float* __restrict__ Wk, const float* __restrict__ Wv,
    const float* __restrict__ W1, const float* __restrict__ W2,
    ushort* __restrict__ dq, ushort* __restrict__ dk, ushort* __restrict__ dv,
    ushort* __restrict__ d1, ushort* __restrict__ d2,
    int* __restrict__ count)
{
    int i = blockIdx.x * 256 + threadIdx.x;
    if (i < 5 * 16384) {
        int w = i >> 14;
        int o = i & 16383;
        int j    = o & 7;
        int lane = (o >> 3) & 63;
        int f    = o >> 9;                 // 0..31
        int t    = f & 7, ks = f >> 3;
        int row  = t * 16 + (lane & 15);
        int col  = ks * 32 + (lane >> 4) * 8 + j;
        const float* s[5] = {Wq, Wk, Wv, W1, W2};
        ushort*      d[5] = {dq, dk, dv, d1, d2};
        d[w][o] = f32_to_bf16(s[w][row * HID + col]);
    }
    if (i < N_NODES) count[i] = 0;
}

// ---------------------------------------------------------------------------
// Linear LDS stage of a fragment-ordered bf16 weight (32 KB), fully coalesced.
// ---------------------------------------------------------------------------
__device__ __forceinline__ void stage_w_lin(const ushort* __restrict__ Wf,
                                            ushort* __restrict__ lds, int tid)
{
    #pragma unroll
    for (int i = 0; i < 8; ++i) {
        int idx = (i * 256 + tid) * 8;
        *(uint4*)(lds + idx) = *(const uint4*)(Wf + idx);
    }
}

// ---------------------------------------------------------------------------
// Q/K/V projection via bf16 MFMA, LDS-staged (linear copy) weights,
// 128 rows/block.  q and v go into the INTERLEAVED qv buffer (node stride
// 256: q then v); k goes into its own [node][128] array.
// ---------------------------------------------------------------------------
__global__ __launch_bounds__(256) void qkv_mfma_kernel(
    const float* __restrict__ feats,
    const ushort* __restrict__ Wq16, const ushort* __restrict__ Wk16, const ushort* __restrict__ Wv16,
    ushort* __restrict__ qv16, ushort* __restrict__ k16)
{
    __shared__ ushort wlds[16384];                 // 32 KB, one W at a time
    const int tid  = threadIdx.x;
    const int wave = tid >> 6;
    const int lane = tid & 63;
    const int row0 = blockIdx.x * 128 + wave * 32;
    const int lrow = lane & 15;
    const int lk   = (lane >> 4) * 8;
    const int crow = (lane >> 4) * 4;

    // A fragments for 2 tiles x 4 ks, converted fp32->bf16 in-reg (N%16==0).
    short8 afrag[2][4];
    bool tvalid[2];
    #pragma unroll
    for (int r = 0; r < 2; ++r) {
        int rr = row0 + r * 16;
        tvalid[r] = (rr < N_NODES);
        const float* arow = feats + (size_t)((tvalid[r] ? rr : 0) + lrow) * HID + lk;
        #pragma unroll
        for (int ks = 0; ks < 4; ++ks) {
            float4 f0 = *(const float4*)(arow + ks * 32);
            float4 f1 = *(const float4*)(arow + ks * 32 + 4);
            short8 a;
            a[0] = (short)f32_to_bf16(f0.x); a[1] = (short)f32_to_bf16(f0.y);
            a[2] = (short)f32_to_bf16(f0.z); a[3] = (short)f32_to_bf16(f0.w);
            a[4] = (short)f32_to_bf16(f1.x); a[5] = (short)f32_to_bf16(f1.y);
            a[6] = (short)f32_to_bf16(f1.z); a[7] = (short)f32_to_bf16(f1.w);
            afrag[r][ks] = a;
        }
    }

    const ushort* Ws[3] = {Wq16, Wk16, Wv16};
    // output bases and per-node strides: q -> qv+0 (256), k -> k16 (128), v -> qv+128 (256)
    ushort* Ob[3]; int Ostride[3];
    Ob[0] = qv16;       Ostride[0] = 256;
    Ob[1] = k16;        Ostride[1] = 128;
    Ob[2] = qv16 + 128; Ostride[2] = 256;

    #pragma unroll
    for (int w = 0; w < 3; ++w) {
        __syncthreads();                           // prior reads of wlds done
        stage_w_lin(Ws[w], wlds, tid);
        __syncthreads();

        floatx4 acc[2][8];
        #pragma unroll
        for (int r = 0; r < 2; ++r)
            #pragma unroll
            for (int t = 0; t < 8; ++t) acc[r][t] = (floatx4)(0.f);

        #pragma unroll
        for (int ks = 0; ks < 4; ++ks) {
            short8 B[8];
            #pragma unroll
            for (int t = 0; t < 8; ++t)
                B[t] = *(const short8*)&wlds[(ks * 8 + t) * 512 + lane * 8];
            #pragma unroll
            for (int t = 0; t < 8; ++t) {
                acc[0][t] = __builtin_amdgcn_mfma_f32_16x16x32_bf16(B[t], afrag[0][ks], acc[0][t], 0, 0, 0);
                acc[1][t] = __builtin_amdgcn_mfma_f32_16x16x32_bf16(B[t], afrag[1][ks], acc[1][t], 0, 0, 0);
            }
        }

        #pragma unroll
        for (int r = 0; r < 2; ++r) {
            if (tvalid[r]) {
                ushort* O = Ob[w] + (size_t)(row0 + r * 16 + lrow) * Ostride[w];
                #pragma unroll
                for (int t = 0; t < 8; ++t) {
                    ushort4 o;
                    o.x = f32_to_bf16(acc[r][t][0]); o.y = f32_to_bf16(acc[r][t][1]);
                    o.z = f32_to_bf16(acc[r][t][2]); o.w = f32_to_bf16(acc[r][t][3]);
                    *(ushort4*)(O + t * 16 + crow) = o;
                }
            }
        }
    }
}

// ---------------------------------------------------------------------------
// CSR build: standalone histogram (slim blocks, full occupancy) -> blocksum
// -> scan_write (folds the top-level scan) -> fill (stores kj direct).
// ---------------------------------------------------------------------------
__global__ __launch_bounds__(256) void hist_kernel(
    const int* __restrict__ idx_ji, int* __restrict__ count)
{
    int m = blockIdx.x * 256 + threadIdx.x;
    if (m < M_EDGES) atomicAdd(&count[idx_ji[m]], 1);
}

__global__ __launch_bounds__(256) void scan_blocksum_kernel(
    const int* __restrict__ count, int* __restrict__ blocksum)
{
    __shared__ int s[256];
    const int tid = threadIdx.x;
    const int base = blockIdx.x * 1024 + tid * 4;
    int sum = 0;
    if (base + 3 < N_NODES) {
        int4 c = *(const int4*)(count + base);
        sum = c.x + c.y + c.z + c.w;
    } else {
        #pragma unroll
        for (int j = 0; j < 4; ++j) if (base + j < N_NODES) sum += count[base + j];
    }
    s[tid] = sum;
    __syncthreads();
    for (int off = 128; off > 0; off >>= 1) {
        if (tid < off) s[tid] += s[tid + off];
        __syncthreads();
    }
    if (tid == 0) blocksum[blockIdx.x] = s[0];
}

__global__ __launch_bounds__(256) void scan_write_kernel(
    const int* __restrict__ count, const int* __restrict__ blocksum,
    int* __restrict__ offsets, int* __restrict__ cursor)
{
    __shared__ int s[256];
    __shared__ int sb[256];
    const int tid = threadIdx.x;
    const int base = blockIdx.x * 1024 + tid * 4;

    // folded scan_top: sb[0] = sum of blocksum[0 .. blockIdx.x-1]
    sb[tid] = (tid < (int)blockIdx.x && tid < SCAN_NB) ? blocksum[tid] : 0;
    __syncthreads();
    for (int off = 128; off > 0; off >>= 1) {
        if (tid < off) sb[tid] += sb[tid + off];
        __syncthreads();
    }
    const int bbase = sb[0];

    int c0 = 0, c1 = 0, c2 = 0, c3 = 0;
    if (base + 3 < N_NODES) {
        int4 c = *(const int4*)(count + base);
        c0 = c.x; c1 = c.y; c2 = c.z; c3 = c.w;
    } else {
        if (base     < N_NODES) c0 = count[base];
        if (base + 1 < N_NODES) c1 = count[base + 1];
        if (base + 2 < N_NODES) c2 = count[base + 2];
        if (base + 3 < N_NODES) c3 = count[base + 3];
    }
    const int tsum = c0 + c1 + c2 + c3;
    s[tid] = tsum;
    __syncthreads();
    for (int off = 1; off < 256; off <<= 1) {
        int x = (tid >= off) ? s[tid - off] : 0;
        __syncthreads();
        s[tid] += x;
        __syncthreads();
    }
    int o0 = s[tid] - tsum + bbase;
    int o1 = o0 + c0, o2 = o1 + c1, o3 = o2 + c2;
    if (base + 3 < N_NODES) {
        *(int4*)(offsets + base) = make_int4(o0, o1, o2, o3);
        *(int4*)(cursor  + base) = make_int4(o0, o1, o2, o3);
    } else {
        if (base     < N_NODES) { offsets[base]     = o0; cursor[base]     = o0; }
        if (base + 1 < N_NODES) { offsets[base + 1] = o1; cursor[base + 1] = o1; }
        if (base + 2 < N_NODES) { offsets[base + 2] = o2; cursor[base + 2] = o2; }
        if (base + 3 < N_NODES) { offsets[base + 3] = o3; cursor[base + 3] = o3; }
    }
}

__global__ __launch_bounds__(256) void fill_kernel(
    const int* __restrict__ idx_ji, const int* __restrict__ idx_kj,
    int* __restrict__ cursor, int* __restrict__ edge_kj)
{
    int m = blockIdx.x * 256 + threadIdx.x;
    if (m < M_EDGES) {
        int pos = atomicAdd(&cursor[idx_ji[m]], 1);
        edge_kj[pos] = idx_kj[m];
    }
}

// ---------------------------------------------------------------------------
// Fused attention + normalized aggregation: 16 LANES PER NODE (4 nodes/wave),
// 8 channels/lane via uint4 (16B) gathers from the interleaved qv buffer.
// Measured floor: ~64 us, 202 MB fetch @ ~3.6 TB/s beyond-L2 (R0/R2).
// ---------------------------------------------------------------------------
__device__ __forceinline__ float dot8(const uint4& qp, const float* kn) {
    const unsigned int* q = (const unsigned int*)&qp;
    float p = 0.f;
    #pragma unroll
    for (int j = 0; j < 4; ++j)
        p += bf16pair_lo(q[j]) * kn[2*j] + bf16pair_hi(q[j]) * kn[2*j+1];
    return p;
}
__device__ __forceinline__ void axpy8(float* acc, float s, const uint4& vp) {
    const unsigned int* v = (const unsigned int*)&vp;
    #pragma unroll
    for (int j = 0; j < 4; ++j) {
        acc[2*j]   += s * bf16pair_lo(v[j]);
        acc[2*j+1] += s * bf16pair_hi(v[j]);
    }
}

__global__ __launch_bounds__(256) void aggregate_kernel(
    const int* __restrict__ edge_kj, const int* __restrict__ offsets,
    const int* __restrict__ count, const ushort* __restrict__ qv16,
    const ushort* __restrict__ k16, ushort* __restrict__ agg16)
{
    const int gid  = blockIdx.x * 256 + threadIdx.x;
    const int node = gid >> 4;
    const int l16  = threadIdx.x & 15;
    if (node >= N_NODES) return;

    const int deg  = count[node];
    const int base = offsets[node];

    float kn[8];
    {
        uint4 kp = *(const uint4*)(k16 + (size_t)node * HID + l16 * 8);
        const unsigned int* kw = (const unsigned int*)&kp;
        #pragma unroll
        for (int j = 0; j < 4; ++j) {
            kn[2*j]   = bf16pair_lo(kw[j]);
            kn[2*j+1] = bf16pair_hi(kw[j]);
        }
    }

    float acc[8] = {0.f,0.f,0.f,0.f,0.f,0.f,0.f,0.f};
    float d = 0.f;

    const ushort* qvb = qv16 + l16 * 8;

    int e = 0;
    for (; e + 4 <= deg; e += 4) {
        const int kj0 = edge_kj[base + e + 0];
        const int kj1 = edge_kj[base + e + 1];
        const int kj2 = edge_kj[base + e + 2];
        const int kj3 = edge_kj[base + e + 3];
        const ushort* r0 = qvb + (size_t)kj0 * 256;
        const ushort* r1 = qvb + (size_t)kj1 * 256;
        const ushort* r2 = qvb + (size_t)kj2 * 256;
        const ushort* r3 = qvb + (size_t)kj3 * 256;
        uint4 qp0 = *(const uint4*)r0;  uint4 vp0 = *(const uint4*)(r0 + 128);
        uint4 qp1 = *(const uint4*)r1;  uint4 vp1 = *(const uint4*)(r1 + 128);
        uint4 qp2 = *(const uint4*)r2;  uint4 vp2 = *(const uint4*)(r2 + 128);
        uint4 qp3 = *(const uint4*)r3;  uint4 vp3 = *(const uint4*)(r3 + 128);

        float p0 = dot8(qp0, kn);
        float p1 = dot8(qp1, kn);
        float p2 = dot8(qp2, kn);
        float p3 = dot8(qp3, kn);
        p0 += __shfl_xor(p0, 1);
        p1 += __shfl_xor(p1, 1);
        p2 += __shfl_xor(p2, 1);
        p3 += __shfl_xor(p3, 1);
        float s0 = __expf(fmaxf(p0, 0.2f * p0));
        float s1 = __expf(fmaxf(p1, 0.2f * p1));
        float s2 = __expf(fmaxf(p2, 0.2f * p2));
        float s3 = __expf(fmaxf(p3, 0.2f * p3));
        d += (s0 + s1) + (s2 + s3);
        axpy8(acc, s0, vp0);
        axpy8(acc, s1, vp1);
        axpy8(acc, s2, vp2);
        axpy8(acc, s3, vp3);
    }
    if (e + 2 <= deg) {
        const int kj0 = edge_kj[base + e];
        const int kj1 = edge_kj[base + e + 1];
        const ushort* r0 = qvb + (size_t)kj0 * 256;
        const ushort* r1 = qvb + (size_t)kj1 * 256;
        uint4 qp0 = *(const uint4*)r0;  uint4 vp0 = *(const uint4*)(r0 + 128);
        uint4 qp1 = *(const uint4*)r1;  uint4 vp1 = *(const uint4*)(r1 + 128);
        float p0 = dot8(qp0, kn);
        float p1 = dot8(qp1, kn);
        p0 += __shfl_xor(p0, 1);
        p1 += __shfl_xor(p1, 1);
        float s0 = __expf(fmaxf(p0, 0.2f * p0));
        float s1 = __expf(fmaxf(p1, 0.2f * p1));
        d += s0 + s1;
        axpy8(acc, s0, vp0);
        axpy8(acc, s1, vp1);
        e += 2;
    }
    if (e < deg) {
        const int kj0 = edge_kj[base + e];
        const ushort* r0 = qvb + (size_t)kj0 * 256;
        uint4 qp0 = *(const uint4*)r0;  uint4 vp0 = *(const uint4*)(r0 + 128);
        float p0 = dot8(qp0, kn);
        p0 += __shfl_xor(p0, 1);
        float s0 = __expf(fmaxf(p0, 0.2f * p0));
        d += s0;
        axpy8(acc, s0, vp0);
    }

    const float inv = (deg > 0) ? 1.f / d : 0.f;     // deg==0 -> zeros, not NaN
    uint4 o;
    unsigned int* ow = (unsigned int*)&o;
    #pragma unroll
    for (int j = 0; j < 4; ++j)
        ow[j] = (unsigned int)f32_to_bf16(acc[2*j] * inv)
              | ((unsigned int)f32_to_bf16(acc[2*j+1] * inv) << 16);
    *(uint4*)(agg16 + (size_t)node * HID + l16 * 8) = o;
}

// ---------------------------------------------------------------------------
// Residual MLP, single fused kernel.  50 KB LDS (3 blocks/CU vs R0's 2):
// 32 KB weight buffer (W1 then W2, linear stage) + 4.3 KB PER-WAVE h1
// transpose scratch (stride 136 = bank-safe).  The h1 C->A transpose is
// within-wave only -> NO barrier; 3 barriers total (vs 4).
// ---------------------------------------------------------------------------
__global__ __launch_bounds__(256) void mlp_mfma_kernel(
    const ushort* __restrict__ agg16, const ushort* __restrict__ qv16,
    const ushort* __restrict__ W1f, const float* __restrict__ b1,
    const ushort* __restrict__ W2f, const float* __restrict__ b2,
    float* __restrict__ out)
{
    __shared__ ushort wlds[16384];          // 32 KB: W1, then W2
    __shared__ ushort hs[4][16 * 136];      // 4 waves x 4352 B transpose scratch
    const int tid  = threadIdx.x;
    const int wave = tid >> 6;
    const int lane = tid & 63;
    const int row0 = blockIdx.x * 128 + wave * 32;
    const int lrow = lane & 15;
    const int lk   = (lane >> 4) * 8;
    const int crow = (lane >> 4) * 4;

    // phase 0: load agg A-fragments (2 tiles x 4 ks)
    short8 afrag[2][4];
    bool tvalid[2];
    #pragma unroll
    for (int r = 0; r < 2; ++r) {
        int rr = row0 + r * 16;
        tvalid[r] = (rr < N_NODES);
        const ushort* arow = agg16 + (size_t)((tvalid[r] ? rr : 0) + lrow) * HID + lk;
        #pragma unroll
        for (int ks = 0; ks < 4; ++ks)
            afrag[r][ks] = *(const short8*)(arow + ks * 32);
    }

    stage_w_lin(W1f, wlds, tid);
    __syncthreads();

    // phase 1: h1 = relu(agg @ W1.T + b1); per-tile in-wave transpose to A-frags
    short8 hfrag[2][4];
    ushort* sc = &hs[wave][0];
    #pragma unroll
    for (int r = 0; r < 2; ++r) {
        floatx4 acc[8];
        #pragma unroll
        for (int t = 0; t < 8; ++t) acc[t] = (floatx4)(0.f);
        #pragma unroll
        for (int ks = 0; ks < 4; ++ks) {
            short8 B[8];
            #pragma unroll
            for (int t = 0; t < 8; ++t)
                B[t] = *(const short8*)&wlds[(ks * 8 + t) * 512 + lane * 8];
            #pragma unroll
            for (int t = 0; t < 8; ++t)
                acc[t] = __builtin_amdgcn_mfma_f32_16x16x32_bf16(B[t], afrag[r][ks], acc[t], 0, 0, 0);
        }
        // write C-frags (row=lrow, cols t*16+crow..+3) to wave scratch
        #pragma unroll
        for (int t = 0; t < 8; ++t) {
            float4 bias = *(const float4*)(b1 + t * 16 + crow);
            ushort4 o;
            o.x = f32_to_bf16(fmaxf(acc[t][0] + bias.x, 0.f));
            o.y = f32_to_bf16(fmaxf(acc[t][1] + bias.y, 0.f));
            o.z = f32_to_bf16(fmaxf(acc[t][2] + bias.z, 0.f));
            o.w = f32_to_bf16(fmaxf(acc[t][3] + bias.w, 0.f));
            *(ushort4*)(sc + lrow * 136 + t * 16 + crow) = o;
        }
        // same-wave read-back as A-frags (DS pipe is in-order; lgkmcnt handled)
        #pragma unroll
        for (int ks = 0; ks < 4; ++ks)
            hfrag[r][ks] = *(const short8*)(sc + lrow * 136 + ks * 32 + lk);
    }
    __syncthreads();                        // all waves done reading W1
    stage_w_lin(W2f, wlds, tid);            // overwrite with W2
    __syncthreads();

    // phase 2: h2 = relu(h1 @ W2.T + b2); out = v + h2
    {
        floatx4 acc[2][8];
        #pragma unroll
        for (int r = 0; r < 2; ++r)
            #pragma unroll
            for (int t = 0; t < 8; ++t) acc[r][t] = (floatx4)(0.f);
        #pragma unroll
        for (int ks = 0; ks < 4; ++ks) {
            short8 B[8];
            #pragma unroll
            for (int t = 0; t < 8; ++t)
                B[t] = *(const short8*)&wlds[(ks * 8 + t) * 512 + lane * 8];
            #pragma unroll
            for (int t = 0; t < 8; ++t) {
                acc[0][t] = __builtin_amdgcn_mfma_f32_16x16x32_bf16(B[t], hfrag[0][ks], acc[0][t], 0, 0, 0);
                acc[1][t] = __builtin_amdgcn_mfma_f32_16x16x32_bf16(B[t], hfrag[1][ks], acc[1][t], 0, 0, 0);
            }
        }
        #pragma unroll
        for (int r = 0; r < 2; ++r) {
            if (tvalid[r]) {
                const size_t nrow = (size_t)(row0 + r * 16 + lrow);
                const ushort* vrow = qv16 + nrow * 256 + 128;
                float* orow = out + nrow * HID;
                #pragma unroll
                for (int t = 0; t < 8; ++t) {
                    float4 bias = *(const float4*)(b2 + t * 16 + crow);
                    ushort4 vv = *(const ushort4*)(vrow + t * 16 + crow);
                    float4 o;
                    o.x = bf16_bits_to_f32(vv.x) + fmaxf(acc[r][t][0] + bias.x, 0.f);
                    o.y = bf16_bits_to_f32(vv.y) + fmaxf(acc[r][t][1] + bias.y, 0.f);
                    o.z = bf16_bits_to_f32(vv.z) + fmaxf(acc[r][t][2] + bias.z, 0.f);
                    o.w = bf16_bits_to_f32(vv.w) + fmaxf(acc[r][t][3] + bias.w, 0.f);
                    *(float4*)(orow + t * 16 + crow) = o;
                }
            }
        }
    }
}

extern "C" void kernel_launch(void* const* d_in, const int* in_sizes, int n_in,
                              void* d_out, int out_size, void* d_ws, size_t ws_size,
                              hipStream_t stream) {
    const float* feats  = (const float*)d_in[0];
    const int*   idx_kj = (const int*)d_in[1];
    const int*   idx_ji = (const int*)d_in[2];
    const float* Wv     = (const float*)d_in[3];
    const float* Wq     = (const float*)d_in[4];
    const float* Wk     = (const float*)d_in[5];
    const float* W1     = (const float*)d_in[6];
    const float* b1     = (const float*)d_in[7];
    const float* W2     = (const float*)d_in[8];
    const float* b2     = (const float*)d_in[9];
    float* out = (float*)d_out;

    // workspace layout
    ushort* qv16    = (ushort*)d_ws;                        // [N][256]: q | v
    ushort* k16     = qv16    + (size_t)N_NODES * 256;      // [N][128]
    ushort* agg16   = k16     + (size_t)N_NODES * HID;      // [N][128]
    ushort* Wq16    = agg16   + (size_t)N_NODES * HID;      // fragment-ordered bf16
    ushort* Wk16    = Wq16 + HID * HID;
    ushort* Wv16    = Wk16 + HID * HID;
    ushort* W116    = Wv16 + HID * HID;
    ushort* W216    = W116 + HID * HID;
    int* count      = (int*)(W216 + HID * HID);
    int* offsets    = count + N_NODES;
    int* cursor     = offsets + N_NODES;
    int* blocksum   = cursor + N_NODES;
    int* edge_kj    = blocksum + ((SCAN_NB + 3) & ~3);

    // weight cvt (frag order) + count zeroing, one dispatch
    cvt_w_kernel<<<(N_NODES + 255) / 256, 256, 0, stream>>>(
        Wq, Wk, Wv, W1, W2, Wq16, Wk16, Wv16, W116, W216, count);

    qkv_mfma_kernel<<<(N_NODES + 127) / 128, 256, 0, stream>>>(
        feats, Wq16, Wk16, Wv16, qv16, k16);

    hist_kernel<<<(M_EDGES + 255) / 256, 256, 0, stream>>>(idx_ji, count);
    scan_blocksum_kernel<<<SCAN_NB, 256, 0, stream>>>(count, blocksum);
    scan_write_kernel<<<SCAN_NB, 256, 0, stream>>>(count, blocksum, offsets, cursor);
    fill_kernel<<<(M_EDGES + 255) / 256, 256, 0, stream>>>(idx_ji, idx_kj, cursor, edge_kj);

    aggregate_kernel<<<((size_t)N_NODES * 16 + 255) / 256, 256, 0, stream>>>(
        edge_kj, offsets, count, qv16, k16, agg16);

    mlp_mfma_kernel<<<(N_NODES + 127) / 128, 256, 0, stream>>>(
        agg16, qv16, W116, b1, W216, b2, out);
}

// Round 6
// 317.729 us; speedup vs baseline: 1.1259x; 1.0161x over previous
//
#include <hip/hip_runtime.h>
#include <hip/hip_bf16.h>
#include <math.h>

#define N_NODES 100000
#define M_EDGES 800000
#define HID 128
#define HEADS 8
#define DH 16
#define SCAN_NB ((N_NODES + 1023) / 1024)   // 98 blocks of 1024 counts
#define NRT 782                             // row-tiles of 128 rows
#define NQKV (3 * NRT)                      // qkv role blocks (w-major)
#define NHIST ((M_EDGES + 255) / 256)

typedef __attribute__((ext_vector_type(8))) short short8;   // 8 x bf16 (4 VGPRs)
typedef __attribute__((ext_vector_type(4))) float floatx4;  // MFMA accumulator

__device__ __forceinline__ ushort f32_to_bf16(float x) {
    __hip_bfloat16 h = __float2bfloat16(x);   // RNE
    union { __hip_bfloat16 h; ushort u; } c; c.h = h;
    return c.u;
}
__device__ __forceinline__ float bf16_bits_to_f32(ushort u) {
    union { unsigned int i; float f; } c; c.i = ((unsigned int)u) << 16;
    return c.f;
}
__device__ __forceinline__ float bf16pair_lo(unsigned int p) {
    union { unsigned int i; float f; } c; c.i = p << 16; return c.f;
}
__device__ __forceinline__ float bf16pair_hi(unsigned int p) {
    union { unsigned int i; float f; } c; c.i = p & 0xffff0000u; return c.f;
}

// ---------------------------------------------------------------------------
// Convert the five 128x128 weight matrices -> bf16 DIRECTLY IN MFMA B-FRAGMENT
// ORDER (out[(ks*8+t)*512 + lane*8 + j] = W[t*16+(lane&15)][ks*32+(lane>>4)*8+j]).
// Consumers stage with a pure linear copy.  Also zeroes count[] (fused memset).
// ---------------------------------------------------------------------------
__global__ __launch_bounds__(256) void cvt_w_kernel(
    const float* __restrict__ Wq, const float* __restrict__ Wk, const float* __restrict__ Wv,
    const float* __restrict__ W1, const float* __restrict__ W2,
    ushort* __restrict__ dq, ushort* __restrict__ dk, ushort* __restrict__ dv,
    ushort* __restrict__ d1, ushort* __restrict__ d2,
    int* __restrict__ count)
{
    int i = blockIdx.x * 256 + threadIdx.x;
    if (i < 5 * 16384) {
        int w = i >> 14;
        int o = i & 16383;
        int j    = o & 7;
        int lane = (o >> 3) & 63;
        int f    = o >> 9;                 // 0..31
        int t    = f & 7, ks = f >> 3;
        int row  = t * 16 + (lane & 15);
        int col  = ks * 32 + (lane >> 4) * 8 + j;
        const float* s[5] = {Wq, Wk, Wv, W1, W2};
        ushort*      d[5] = {dq, dk, dv, d1, d2};
        d[w][o] = f32_to_bf16(s[w][row * HID + col]);
    }
    if (i < N_NODES) count[i] = 0;
}

// ---------------------------------------------------------------------------
// Linear LDS stage of a fragment-ordered bf16 weight (32 KB), fully coalesced.
// ---------------------------------------------------------------------------
__device__ __forceinline__ void stage_w_lin(const ushort* __restrict__ Wf,
                                            ushort* __restrict__ lds, int tid)
{
    #pragma unroll
    for (int i = 0; i < 8; ++i) {
        int idx = (i * 256 + tid) * 8;
        *(uint4*)(lds + idx) = *(const uint4*)(Wf + idx);
    }
}

// ---------------------------------------------------------------------------
// Q/K/V projection, ONE WEIGHT PER BLOCK (w-major: blocks [0,782) q,
// [782,1564) k, [1564,2346) v).  Per block: 1 stage + 1 barrier (vs 3+6),
// 3x grid -> 5 blocks/CU (LDS cap) with cross-block stage/MFMA pipelining.
// feats re-read 3x is L3-backed (51 MB << 256 MB).
// Blocks >= NQKV are HIST role: count[idx_ji[m]]++ (concurrent, not serial).
// ---------------------------------------------------------------------------
__global__ __launch_bounds__(256) void qkv_hist_kernel(
    const float* __restrict__ feats,
    const ushort* __restrict__ Wq16, const ushort* __restrict__ Wk16, const ushort* __restrict__ Wv16,
    ushort* __restrict__ qv16, ushort* __restrict__ k16,
    const int* __restrict__ idx_ji, int* __restrict__ count)
{
    __shared__ ushort wlds[16384];                 // 32 KB
    const int tid  = threadIdx.x;

    if (blockIdx.x >= NQKV) {                      // ---- hist role ----
        int m = (blockIdx.x - NQKV) * 256 + tid;
        if (m < M_EDGES) atomicAdd(&count[idx_ji[m]], 1);
        return;
    }

    const int w    = blockIdx.x / NRT;             // weight index (stays L2-hot)
    const int rt   = blockIdx.x % NRT;             // row-tile
    const int wave = tid >> 6;
    const int lane = tid & 63;
    const int row0 = rt * 128 + wave * 32;
    const int lrow = lane & 15;
    const int lk   = (lane >> 4) * 8;
    const int crow = (lane >> 4) * 4;

    const ushort* Wf = (w == 0) ? Wq16 : (w == 1) ? Wk16 : Wv16;
    ushort* Ob       = (w == 0) ? qv16 : (w == 1) ? k16  : qv16 + 128;
    const int Ostr   = (w == 1) ? 128 : 256;

    stage_w_lin(Wf, wlds, tid);                    // issue stage early

    // A fragments for 2 tiles x 4 ks, fp32->bf16 in-reg (overlaps stage)
    short8 afrag[2][4];
    bool tvalid[2];
    #pragma unroll
    for (int r = 0; r < 2; ++r) {
        int rr = row0 + r * 16;
        tvalid[r] = (rr < N_NODES);
        const float* arow = feats + (size_t)((tvalid[r] ? rr : 0) + lrow) * HID + lk;
        #pragma unroll
        for (int ks = 0; ks < 4; ++ks) {
            float4 f0 = *(const float4*)(arow + ks * 32);
            float4 f1 = *(const float4*)(arow + ks * 32 + 4);
            short8 a;
            a[0] = (short)f32_to_bf16(f0.x); a[1] = (short)f32_to_bf16(f0.y);
            a[2] = (short)f32_to_bf16(f0.z); a[3] = (short)f32_to_bf16(f0.w);
            a[4] = (short)f32_to_bf16(f1.x); a[5] = (short)f32_to_bf16(f1.y);
            a[6] = (short)f32_to_bf16(f1.z); a[7] = (short)f32_to_bf16(f1.w);
            afrag[r][ks] = a;
        }
    }

    __syncthreads();                               // stage visible

    floatx4 acc[2][8];
    #pragma unroll
    for (int r = 0; r < 2; ++r)
        #pragma unroll
        for (int t = 0; t < 8; ++t) acc[r][t] = (floatx4)(0.f);

    #pragma unroll
    for (int ks = 0; ks < 4; ++ks) {
        short8 B[8];
        #pragma unroll
        for (int t = 0; t < 8; ++t)
            B[t] = *(const short8*)&wlds[(ks * 8 + t) * 512 + lane * 8];
        #pragma unroll
        for (int t = 0; t < 8; ++t) {
            acc[0][t] = __builtin_amdgcn_mfma_f32_16x16x32_bf16(B[t], afrag[0][ks], acc[0][t], 0, 0, 0);
            acc[1][t] = __builtin_amdgcn_mfma_f32_16x16x32_bf16(B[t], afrag[1][ks], acc[1][t], 0, 0, 0);
        }
    }

    #pragma unroll
    for (int r = 0; r < 2; ++r) {
        if (tvalid[r]) {
            ushort* O = Ob + (size_t)(row0 + r * 16 + lrow) * Ostr;
            #pragma unroll
            for (int t = 0; t < 8; ++t) {
                ushort4 o;
                o.x = f32_to_bf16(acc[r][t][0]); o.y = f32_to_bf16(acc[r][t][1]);
                o.z = f32_to_bf16(acc[r][t][2]); o.w = f32_to_bf16(acc[r][t][3]);
                *(ushort4*)(O + t * 16 + crow) = o;
            }
        }
    }
}

// ---------------------------------------------------------------------------
// CSR build: blocksum -> scan_write (folds top-level scan) -> fill.
// ---------------------------------------------------------------------------
__global__ __launch_bounds__(256) void scan_blocksum_kernel(
    const int* __restrict__ count, int* __restrict__ blocksum)
{
    __shared__ int s[256];
    const int tid = threadIdx.x;
    const int base = blockIdx.x * 1024 + tid * 4;
    int sum = 0;
    if (base + 3 < N_NODES) {
        int4 c = *(const int4*)(count + base);
        sum = c.x + c.y + c.z + c.w;
    } else {
        #pragma unroll
        for (int j = 0; j < 4; ++j) if (base + j < N_NODES) sum += count[base + j];
    }
    s[tid] = sum;
    __syncthreads();
    for (int off = 128; off > 0; off >>= 1) {
        if (tid < off) s[tid] += s[tid + off];
        __syncthreads();
    }
    if (tid == 0) blocksum[blockIdx.x] = s[0];
}

__global__ __launch_bounds__(256) void scan_write_kernel(
    const int* __restrict__ count, const int* __restrict__ blocksum,
    int* __restrict__ offsets, int* __restrict__ cursor)
{
    __shared__ int s[256];
    __shared__ int sb[256];
    const int tid = threadIdx.x;
    const int base = blockIdx.x * 1024 + tid * 4;

    // folded scan_top: sb[0] = sum of blocksum[0 .. blockIdx.x-1]
    sb[tid] = (tid < (int)blockIdx.x && tid < SCAN_NB) ? blocksum[tid] : 0;
    __syncthreads();
    for (int off = 128; off > 0; off >>= 1) {
        if (tid < off) sb[tid] += sb[tid + off];
        __syncthreads();
    }
    const int bbase = sb[0];

    int c0 = 0, c1 = 0, c2 = 0, c3 = 0;
    if (base + 3 < N_NODES) {
        int4 c = *(const int4*)(count + base);
        c0 = c.x; c1 = c.y; c2 = c.z; c3 = c.w;
    } else {
        if (base     < N_NODES) c0 = count[base];
        if (base + 1 < N_NODES) c1 = count[base + 1];
        if (base + 2 < N_NODES) c2 = count[base + 2];
        if (base + 3 < N_NODES) c3 = count[base + 3];
    }
    const int tsum = c0 + c1 + c2 + c3;
    s[tid] = tsum;
    __syncthreads();
    for (int off = 1; off < 256; off <<= 1) {
        int x = (tid >= off) ? s[tid - off] : 0;
        __syncthreads();
        s[tid] += x;
        __syncthreads();
    }
    int o0 = s[tid] - tsum + bbase;
    int o1 = o0 + c0, o2 = o1 + c1, o3 = o2 + c2;
    if (base + 3 < N_NODES) {
        *(int4*)(offsets + base) = make_int4(o0, o1, o2, o3);
        *(int4*)(cursor  + base) = make_int4(o0, o1, o2, o3);
    } else {
        if (base     < N_NODES) { offsets[base]     = o0; cursor[base]     = o0; }
        if (base + 1 < N_NODES) { offsets[base + 1] = o1; cursor[base + 1] = o1; }
        if (base + 2 < N_NODES) { offsets[base + 2] = o2; cursor[base + 2] = o2; }
        if (base + 3 < N_NODES) { offsets[base + 3] = o3; cursor[base + 3] = o3; }
    }
}

__global__ __launch_bounds__(256) void fill_kernel(
    const int* __restrict__ idx_ji, const int* __restrict__ idx_kj,
    int* __restrict__ cursor, int* __restrict__ edge_kj)
{
    int m = blockIdx.x * 256 + threadIdx.x;
    if (m < M_EDGES) {
        int pos = atomicAdd(&cursor[idx_ji[m]], 1);
        edge_kj[pos] = idx_kj[m];
    }
}

// ---------------------------------------------------------------------------
// Fused attention + normalized aggregation: 16 LANES PER NODE (4 nodes/wave),
// 8 channels/lane via uint4 (16B) gathers from the interleaved qv buffer.
// Measured floor: ~64 us, 202 MB fetch @ ~3.6 TB/s beyond-L2 (R0/R2/R5).
// ---------------------------------------------------------------------------
__device__ __forceinline__ float dot8(const uint4& qp, const float* kn) {
    const unsigned int* q = (const unsigned int*)&qp;
    float p = 0.f;
    #pragma unroll
    for (int j = 0; j < 4; ++j)
        p += bf16pair_lo(q[j]) * kn[2*j] + bf16pair_hi(q[j]) * kn[2*j+1];
    return p;
}
__device__ __forceinline__ void axpy8(float* acc, float s, const uint4& vp) {
    const unsigned int* v = (const unsigned int*)&vp;
    #pragma unroll
    for (int j = 0; j < 4; ++j) {
        acc[2*j]   += s * bf16pair_lo(v[j]);
        acc[2*j+1] += s * bf16pair_hi(v[j]);
    }
}

__global__ __launch_bounds__(256) void aggregate_kernel(
    const int* __restrict__ edge_kj, const int* __restrict__ offsets,
    const int* __restrict__ count, const ushort* __restrict__ qv16,
    const ushort* __restrict__ k16, ushort* __restrict__ agg16)
{
    const int gid  = blockIdx.x * 256 + threadIdx.x;
    const int node = gid >> 4;
    const int l16  = threadIdx.x & 15;
    if (node >= N_NODES) return;

    const int deg  = count[node];
    const int base = offsets[node];

    float kn[8];
    {
        uint4 kp = *(const uint4*)(k16 + (size_t)node * HID + l16 * 8);
        const unsigned int* kw = (const unsigned int*)&kp;
        #pragma unroll
        for (int j = 0; j < 4; ++j) {
            kn[2*j]   = bf16pair_lo(kw[j]);
            kn[2*j+1] = bf16pair_hi(kw[j]);
        }
    }

    float acc[8] = {0.f,0.f,0.f,0.f,0.f,0.f,0.f,0.f};
    float d = 0.f;

    const ushort* qvb = qv16 + l16 * 8;

    int e = 0;
    for (; e + 4 <= deg; e += 4) {
        const int kj0 = edge_kj[base + e + 0];
        const int kj1 = edge_kj[base + e + 1];
        const int kj2 = edge_kj[base + e + 2];
        const int kj3 = edge_kj[base + e + 3];
        const ushort* r0 = qvb + (size_t)kj0 * 256;
        const ushort* r1 = qvb + (size_t)kj1 * 256;
        const ushort* r2 = qvb + (size_t)kj2 * 256;
        const ushort* r3 = qvb + (size_t)kj3 * 256;
        uint4 qp0 = *(const uint4*)r0;  uint4 vp0 = *(const uint4*)(r0 + 128);
        uint4 qp1 = *(const uint4*)r1;  uint4 vp1 = *(const uint4*)(r1 + 128);
        uint4 qp2 = *(const uint4*)r2;  uint4 vp2 = *(const uint4*)(r2 + 128);
        uint4 qp3 = *(const uint4*)r3;  uint4 vp3 = *(const uint4*)(r3 + 128);

        float p0 = dot8(qp0, kn);
        float p1 = dot8(qp1, kn);
        float p2 = dot8(qp2, kn);
        float p3 = dot8(qp3, kn);
        p0 += __shfl_xor(p0, 1);
        p1 += __shfl_xor(p1, 1);
        p2 += __shfl_xor(p2, 1);
        p3 += __shfl_xor(p3, 1);
        float s0 = __expf(fmaxf(p0, 0.2f * p0));
        float s1 = __expf(fmaxf(p1, 0.2f * p1));
        float s2 = __expf(fmaxf(p2, 0.2f * p2));
        float s3 = __expf(fmaxf(p3, 0.2f * p3));
        d += (s0 + s1) + (s2 + s3);
        axpy8(acc, s0, vp0);
        axpy8(acc, s1, vp1);
        axpy8(acc, s2, vp2);
        axpy8(acc, s3, vp3);
    }
    if (e + 2 <= deg) {
        const int kj0 = edge_kj[base + e];
        const int kj1 = edge_kj[base + e + 1];
        const ushort* r0 = qvb + (size_t)kj0 * 256;
        const ushort* r1 = qvb + (size_t)kj1 * 256;
        uint4 qp0 = *(const uint4*)r0;  uint4 vp0 = *(const uint4*)(r0 + 128);
        uint4 qp1 = *(const uint4*)r1;  uint4 vp1 = *(const uint4*)(r1 + 128);
        float p0 = dot8(qp0, kn);
        float p1 = dot8(qp1, kn);
        p0 += __shfl_xor(p0, 1);
        p1 += __shfl_xor(p1, 1);
        float s0 = __expf(fmaxf(p0, 0.2f * p0));
        float s1 = __expf(fmaxf(p1, 0.2f * p1));
        d += s0 + s1;
        axpy8(acc, s0, vp0);
        axpy8(acc, s1, vp1);
        e += 2;
    }
    if (e < deg) {
        const int kj0 = edge_kj[base + e];
        const ushort* r0 = qvb + (size_t)kj0 * 256;
        uint4 qp0 = *(const uint4*)r0;  uint4 vp0 = *(const uint4*)(r0 + 128);
        float p0 = dot8(qp0, kn);
        p0 += __shfl_xor(p0, 1);
        float s0 = __expf(fmaxf(p0, 0.2f * p0));
        d += s0;
        axpy8(acc, s0, vp0);
    }

    const float inv = (deg > 0) ? 1.f / d : 0.f;     // deg==0 -> zeros, not NaN
    uint4 o;
    unsigned int* ow = (unsigned int*)&o;
    #pragma unroll
    for (int j = 0; j < 4; ++j)
        ow[j] = (unsigned int)f32_to_bf16(acc[2*j] * inv)
              | ((unsigned int)f32_to_bf16(acc[2*j+1] * inv) << 16);
    *(uint4*)(agg16 + (size_t)node * HID + l16 * 8) = o;
}

// ---------------------------------------------------------------------------
// Residual MLP, single fused kernel (R5 form, measured good).  50 KB LDS:
// 32 KB weight buffer (W1 then W2, linear stage) + 4.3 KB PER-WAVE h1
// transpose scratch (stride 136 = bank-safe, in-wave only -> no barrier).
// ---------------------------------------------------------------------------
__global__ __launch_bounds__(256) void mlp_mfma_kernel(
    const ushort* __restrict__ agg16, const ushort* __restrict__ qv16,
    const ushort* __restrict__ W1f, const float* __restrict__ b1,
    const ushort* __restrict__ W2f, const float* __restrict__ b2,
    float* __restrict__ out)
{
    __shared__ ushort wlds[16384];          // 32 KB: W1, then W2
    __shared__ ushort hs[4][16 * 136];      // 4 waves x 4352 B transpose scratch
    const int tid  = threadIdx.x;
    const int wave = tid >> 6;
    const int lane = tid & 63;
    const int row0 = blockIdx.x * 128 + wave * 32;
    const int lrow = lane & 15;
    const int lk   = (lane >> 4) * 8;
    const int crow = (lane >> 4) * 4;

    // phase 0: load agg A-fragments (2 tiles x 4 ks)
    short8 afrag[2][4];
    bool tvalid[2];
    #pragma unroll
    for (int r = 0; r < 2; ++r) {
        int rr = row0 + r * 16;
        tvalid[r] = (rr < N_NODES);
        const ushort* arow = agg16 + (size_t)((tvalid[r] ? rr : 0) + lrow) * HID + lk;
        #pragma unroll
        for (int ks = 0; ks < 4; ++ks)
            afrag[r][ks] = *(const short8*)(arow + ks * 32);
    }

    stage_w_lin(W1f, wlds, tid);
    __syncthreads();

    // phase 1: h1 = relu(agg @ W1.T + b1); per-tile in-wave transpose to A-frags
    short8 hfrag[2][4];
    ushort* sc = &hs[wave][0];
    #pragma unroll
    for (int r = 0; r < 2; ++r) {
        floatx4 acc[8];
        #pragma unroll
        for (int t = 0; t < 8; ++t) acc[t] = (floatx4)(0.f);
        #pragma unroll
        for (int ks = 0; ks < 4; ++ks) {
            short8 B[8];
            #pragma unroll
            for (int t = 0; t < 8; ++t)
                B[t] = *(const short8*)&wlds[(ks * 8 + t) * 512 + lane * 8];
            #pragma unroll
            for (int t = 0; t < 8; ++t)
                acc[t] = __builtin_amdgcn_mfma_f32_16x16x32_bf16(B[t], afrag[r][ks], acc[t], 0, 0, 0);
        }
        #pragma unroll
        for (int t = 0; t < 8; ++t) {
            float4 bias = *(const float4*)(b1 + t * 16 + crow);
            ushort4 o;
            o.x = f32_to_bf16(fmaxf(acc[t][0] + bias.x, 0.f));
            o.y = f32_to_bf16(fmaxf(acc[t][1] + bias.y, 0.f));
            o.z = f32_to_bf16(fmaxf(acc[t][2] + bias.z, 0.f));
            o.w = f32_to_bf16(fmaxf(acc[t][3] + bias.w, 0.f));
            *(ushort4*)(sc + lrow * 136 + t * 16 + crow) = o;
        }
        #pragma unroll
        for (int ks = 0; ks < 4; ++ks)
            hfrag[r][ks] = *(const short8*)(sc + lrow * 136 + ks * 32 + lk);
    }
    __syncthreads();                        // all waves done reading W1
    stage_w_lin(W2f, wlds, tid);            // overwrite with W2
    __syncthreads();

    // phase 2: h2 = relu(h1 @ W2.T + b2); out = v + h2
    {
        floatx4 acc[2][8];
        #pragma unroll
        for (int r = 0; r < 2; ++r)
            #pragma unroll
            for (int t = 0; t < 8; ++t) acc[r][t] = (floatx4)(0.f);
        #pragma unroll
        for (int ks = 0; ks < 4; ++ks) {
            short8 B[8];
            #pragma unroll
            for (int t = 0; t < 8; ++t)
                B[t] = *(const short8*)&wlds[(ks * 8 + t) * 512 + lane * 8];
            #pragma unroll
            for (int t = 0; t < 8; ++t) {
                acc[0][t] = __builtin_amdgcn_mfma_f32_16x16x32_bf16(B[t], hfrag[0][ks], acc[0][t], 0, 0, 0);
                acc[1][t] = __builtin_amdgcn_mfma_f32_16x16x32_bf16(B[t], hfrag[1][ks], acc[1][t], 0, 0, 0);
            }
        }
        #pragma unroll
        for (int r = 0; r < 2; ++r) {
            if (tvalid[r]) {
                const size_t nrow = (size_t)(row0 + r * 16 + lrow);
                const ushort* vrow = qv16 + nrow * 256 + 128;
                float* orow = out + nrow * HID;
                #pragma unroll
                for (int t = 0; t < 8; ++t) {
                    float4 bias = *(const float4*)(b2 + t * 16 + crow);
                    ushort4 vv = *(const ushort4*)(vrow + t * 16 + crow);
                    float4 o;
                    o.x = bf16_bits_to_f32(vv.x) + fmaxf(acc[r][t][0] + bias.x, 0.f);
                    o.y = bf16_bits_to_f32(vv.y) + fmaxf(acc[r][t][1] + bias.y, 0.f);
                    o.z = bf16_bits_to_f32(vv.z) + fmaxf(acc[r][t][2] + bias.z, 0.f);
                    o.w = bf16_bits_to_f32(vv.w) + fmaxf(acc[r][t][3] + bias.w, 0.f);
                    *(float4*)(orow + t * 16 + crow) = o;
                }
            }
        }
    }
}

extern "C" void kernel_launch(void* const* d_in, const int* in_sizes, int n_in,
                              void* d_out, int out_size, void* d_ws, size_t ws_size,
                              hipStream_t stream) {
    const float* feats  = (const float*)d_in[0];
    const int*   idx_kj = (const int*)d_in[1];
    const int*   idx_ji = (const int*)d_in[2];
    const float* Wv     = (const float*)d_in[3];
    const float* Wq     = (const float*)d_in[4];
    const float* Wk     = (const float*)d_in[5];
    const float* W1     = (const float*)d_in[6];
    const float* b1     = (const float*)d_in[7];
    const float* W2     = (const float*)d_in[8];
    const float* b2     = (const float*)d_in[9];
    float* out = (float*)d_out;

    // workspace layout
    ushort* qv16    = (ushort*)d_ws;                        // [N][256]: q | v
    ushort* k16     = qv16    + (size_t)N_NODES * 256;      // [N][128]
    ushort* agg16   = k16     + (size_t)N_NODES * HID;      // [N][128]
    ushort* Wq16    = agg16   + (size_t)N_NODES * HID;      // fragment-ordered bf16
    ushort* Wk16    = Wq16 + HID * HID;
    ushort* Wv16    = Wk16 + HID * HID;
    ushort* W116    = Wv16 + HID * HID;
    ushort* W216    = W116 + HID * HID;
    int* count      = (int*)(W216 + HID * HID);
    int* offsets    = count + N_NODES;
    int* cursor     = offsets + N_NODES;
    int* blocksum   = cursor + N_NODES;
    int* edge_kj    = blocksum + ((SCAN_NB + 3) & ~3);

    // weight cvt (frag order) + count zeroing, one dispatch
    cvt_w_kernel<<<(N_NODES + 255) / 256, 256, 0, stream>>>(
        Wq, Wk, Wv, W1, W2, Wq16, Wk16, Wv16, W116, W216, count);

    // qkv (one weight per block) CONCURRENT with edge histogram (role split)
    qkv_hist_kernel<<<NQKV + NHIST, 256, 0, stream>>>(
        feats, Wq16, Wk16, Wv16, qv16, k16, idx_ji, count);

    scan_blocksum_kernel<<<SCAN_NB, 256, 0, stream>>>(count, blocksum);
    scan_write_kernel<<<SCAN_NB, 256, 0, stream>>>(count, blocksum, offsets, cursor);
    fill_kernel<<<(M_EDGES + 255) / 256, 256, 0, stream>>>(idx_ji, idx_kj, cursor, edge_kj);

    aggregate_kernel<<<((size_t)N_NODES * 16 + 255) / 256, 256, 0, stream>>>(
        edge_kj, offsets, count, qv16, k16, agg16);

    mlp_mfma_kernel<<<(N_NODES + 127) / 128, 256, 0, stream>>>(
        agg16, qv16, W116, b1, W216, b2, out);
}